// Round 3
// baseline (292.045 us; speedup 1.0000x reference)
//
#include <hip/hip_runtime.h>
#include <hip/hip_bf16.h>

#define N_NODE 100000
#define N_NET  20000
#define NE     200000
#define H_NODE 64
#define H_NET  32
#define H_PIN  16
#define O_NODE 32
#define O_NET  64

// ---------------- workspace layout (bytes) ----------------
// node_deg : int   [N_NODE]            off 0          400000
// net_deg  : int   [N_NET]             off 400000      80000
// agg      : float [N_NET*64]          off 480000    5120000
// acc_node : float [N_NODE*32]         off 5600000  12800000
// Z        : float [N_NET*512]         off 18400000 40960000
// C        : float [N_NET*32]          off 59360000  2560000
// total 61,920,000 bytes. First 18,400,000 bytes must be zeroed (atomics).

#define OFF_NETDEG 400000
#define OFF_AGG    480000
#define OFF_ACCN   5600000
#define OFF_Z      18400000
#define OFF_C      59360000
#define ZERO_BYTES 18400000

__global__ void k_deg(const int* __restrict__ en, const int* __restrict__ em,
                      int* __restrict__ node_deg, int* __restrict__ net_deg) {
    int e = blockIdx.x * blockDim.x + threadIdx.x;
    if (e < NE) {
        atomicAdd(&node_deg[en[e]], 1);
        atomicAdd(&net_deg[em[e]], 1);
    }
}

// pins: scatter node_feat * rsqrt(out_deg) into agg[net]. 64 lanes per edge.
__global__ void k_agg(const float* __restrict__ node_feat,
                      const int* __restrict__ en, const int* __restrict__ em,
                      const int* __restrict__ node_deg, float* __restrict__ agg) {
    int idx = blockIdx.x * blockDim.x + threadIdx.x;
    int e = idx >> 6;
    int h = idx & 63;
    if (e >= NE) return;
    int v = en[e], n = em[e];
    float d = (float)node_deg[v]; if (d < 1.f) d = 1.f;
    float s = rsqrtf(d);
    float val = node_feat[v * H_NODE + h] * s;
    atomicAdd(&agg[n * H_NODE + h], val);
}

// net_out = (agg * rsqrt(in_deg)) @ W1 + b1   [N_NET,64]x[64,64]
__global__ void k_netout(const float* __restrict__ agg, const int* __restrict__ net_deg,
                         const float* __restrict__ W1,
                         const float* __restrict__ b1,
                         float* __restrict__ out_net) {
    __shared__ float sW[H_NODE * O_NET]; // 16 KB
    int t = threadIdx.x;
    for (int i = t; i < H_NODE * O_NET; i += 256) sW[i] = W1[i];
    __syncthreads();
    int idx = blockIdx.x * 256 + t;
    if (idx >= N_NET * O_NET) return;
    int n = idx >> 6, o = idx & 63;
    float d = (float)net_deg[n]; if (d < 1.f) d = 1.f;
    float s = rsqrtf(d);
    const float* arow = &agg[n * H_NODE];
    float acc = 0.f;
#pragma unroll
    for (int h = 0; h < H_NODE; h++) acc += arow[h] * sW[h * O_NET + o];
    out_net[idx] = acc * s + b1[o];
}

// Z[n,k,o] = sum_i net_feat[n,i] * W2[k, i*32+o]   (per-net precompute)
// C[n,o]   = sum_i net_feat[n,i] * b2[i*32+o]
#define NPB 8
__global__ void k_z(const float* __restrict__ net_feat,
                    const float* __restrict__ W2,
                    const float* __restrict__ b2,
                    float* __restrict__ Z, float* __restrict__ C) {
    __shared__ float sy[NPB * H_NET]; // 1 KB
    int t = threadIdx.x;
    int base = blockIdx.x * NPB;
    if (t < NPB * H_NET) {
        int n = base + (t >> 5);
        sy[t] = (n < N_NET) ? net_feat[n * H_NET + (t & 31)] : 0.f;
    }
    __syncthreads();
    for (int j = 0; j < NPB; j++) {
        int n = base + j;
        if (n >= N_NET) break;
        const float* y = &sy[j * H_NET];
#pragma unroll
        for (int r = 0; r < 2; r++) {
            int ko = t + r * 256;        // 0..511
            int k = ko >> 5, o = ko & 31;
            float acc = 0.f;
#pragma unroll
            for (int i = 0; i < H_NET; i++)
                acc += y[i] * W2[k * 1024 + i * 32 + o];
            Z[n * 512 + ko] = acc;
        }
        if (t < 32) {
            float acc = 0.f;
#pragma unroll
            for (int i = 0; i < H_NET; i++)
                acc += y[i] * b2[i * 32 + t];
            C[n * 32 + t] = acc;
        }
    }
}

// per-edge: msg[e,o] = C[n,o] + sum_k p[e,k]*Z[n,k,o]; scatter into acc_node[v]
__global__ void k_msg(const float* __restrict__ pin_feat,
                      const int* __restrict__ en, const int* __restrict__ em,
                      const float* __restrict__ Z, const float* __restrict__ C,
                      float* __restrict__ acc_node) {
    int idx = blockIdx.x * blockDim.x + threadIdx.x;
    int e = idx >> 5;
    int o = idx & 31;
    if (e >= NE) return;
    int n = em[e], v = en[e];
    const float* z = &Z[n * 512 + o];
    float m = C[n * 32 + o];
    const float* p = &pin_feat[e * H_PIN];
#pragma unroll
    for (int k = 0; k < H_PIN; k++)
        m += p[k] * z[k * 32];
    atomicAdd(&acc_node[v * O_NODE + o], m);
}

__global__ void k_nodeout(const float* __restrict__ acc_node,
                          const int* __restrict__ node_deg,
                          const float* __restrict__ b_nn,
                          float* __restrict__ out_node) {
    int idx = blockIdx.x * blockDim.x + threadIdx.x;
    if (idx >= N_NODE * O_NODE) return;
    int v = idx >> 5, o = idx & 31;
    float d = (float)node_deg[v]; if (d < 1.f) d = 1.f;
    out_node[idx] = acc_node[idx] / d + b_nn[o];
}

extern "C" void kernel_launch(void* const* d_in, const int* in_sizes, int n_in,
                              void* d_out, int out_size, void* d_ws, size_t ws_size,
                              hipStream_t stream) {
    const float* node_feat = (const float*)d_in[0];
    const float* net_feat  = (const float*)d_in[1];
    const float* pin_feat  = (const float*)d_in[2];
    const int*   edge_node = (const int*)d_in[3];
    const int*   edge_net  = (const int*)d_in[4];
    const float* W1        = (const float*)d_in[5];
    const float* b1        = (const float*)d_in[6];
    const float* W2        = (const float*)d_in[7];
    const float* b2        = (const float*)d_in[8];
    const float* b_nn      = (const float*)d_in[9];

    float* out_node = (float*)d_out;                          // [N_NODE*32]
    float* out_net  = out_node + (size_t)N_NODE * O_NODE;     // [N_NET*64]

    char* ws = (char*)d_ws;
    int*   node_deg = (int*)ws;
    int*   net_deg  = (int*)(ws + OFF_NETDEG);
    float* agg      = (float*)(ws + OFF_AGG);
    float* acc_node = (float*)(ws + OFF_ACCN);
    float* Z        = (float*)(ws + OFF_Z);
    float* C        = (float*)(ws + OFF_C);

    (void)hipMemsetAsync(ws, 0, ZERO_BYTES, stream);

    k_deg<<<(NE + 255) / 256, 256, 0, stream>>>(edge_node, edge_net, node_deg, net_deg);

    k_agg<<<((size_t)NE * 64 + 255) / 256, 256, 0, stream>>>(
        node_feat, edge_node, edge_net, node_deg, agg);

    k_netout<<<(N_NET * O_NET + 255) / 256, 256, 0, stream>>>(
        agg, net_deg, W1, b1, out_net);

    k_z<<<(N_NET + NPB - 1) / NPB, 256, 0, stream>>>(net_feat, W2, b2, Z, C);

    k_msg<<<((size_t)NE * 32 + 255) / 256, 256, 0, stream>>>(
        pin_feat, edge_node, edge_net, Z, C, acc_node);

    k_nodeout<<<(N_NODE * O_NODE + 255) / 256, 256, 0, stream>>>(
        acc_node, node_deg, b_nn, out_node);
}

// Round 4
// 282.552 us; speedup vs baseline: 1.0336x; 1.0336x over previous
//
#include <hip/hip_runtime.h>
#include <hip/hip_bf16.h>

#define N_NODE 100000
#define N_NET  20000
#define NE     200000
#define H_NODE 64
#define H_NET  32
#define H_PIN  16
#define O_NODE 32
#define O_NET  64

// ---------------- workspace layout (bytes) ----------------
// zeroed region: [0, 13,280,000)
//   node_deg : int   [N_NODE]   off 0          (400000)
//   net_deg  : int   [N_NET]    off 400000     (80000)
//   acc_node : float [N_NODE*32] off 480000    (12800000)
// net_ptr   : int  [N_NET+1]    off 13280000   (80004)
// net_cursor: int  [N_NET]      off 13360008   (80000)
// csr       : int2 [NE]         off 13440008   (1600000)
// Z         : float[N_NET*512]  off 15040016   (40960000)
// C         : float[N_NET*32]   off 56000016   (2560000)
// total 58,560,016 bytes (ws held >= 61.92MB last round)

#define OFF_NETDEG  400000
#define OFF_ACCN    480000
#define OFF_NETPTR  13280000
#define OFF_CURSOR  13360008
#define OFF_CSR     13440008
#define OFF_Z       15040016
#define OFF_C       56000016
#define ZERO_BYTES  13280000

__global__ void k_deg(const int* __restrict__ en, const int* __restrict__ em,
                      int* __restrict__ node_deg, int* __restrict__ net_deg) {
    int e = blockIdx.x * blockDim.x + threadIdx.x;
    if (e < NE) {
        atomicAdd(&node_deg[en[e]], 1);
        atomicAdd(&net_deg[em[e]], 1);
    }
}

// single-block exclusive scan of net_deg -> net_ptr; also init net_cursor
__global__ void k_scan(const int* __restrict__ net_deg, int* __restrict__ net_ptr,
                       int* __restrict__ net_cursor) {
    __shared__ int part[256];
    int t = threadIdx.x;
    const int CH = (N_NET + 255) / 256; // 79
    int lo = t * CH, hi = lo + CH; if (hi > N_NET) hi = N_NET; if (lo > N_NET) lo = N_NET;
    int s = 0;
    for (int i = lo; i < hi; i++) s += net_deg[i];
    part[t] = s;
    __syncthreads();
    for (int off = 1; off < 256; off <<= 1) {
        int v = (t >= off) ? part[t - off] : 0;
        __syncthreads();
        part[t] += v;
        __syncthreads();
    }
    int run = (t == 0) ? 0 : part[t - 1];
    for (int i = lo; i < hi; i++) {
        net_ptr[i] = run;
        net_cursor[i] = run;
        run += net_deg[i];
    }
    if (t == 255) net_ptr[N_NET] = run;
}

// scatter {edge,node} pairs into net-CSR
__global__ void k_fill(const int* __restrict__ en, const int* __restrict__ em,
                       int* __restrict__ net_cursor, int2* __restrict__ csr) {
    int e = blockIdx.x * blockDim.x + threadIdx.x;
    if (e < NE) {
        int slot = atomicAdd(&net_cursor[em[e]], 1);
        csr[slot] = make_int2(e, en[e]);
    }
}

// fused: per-net gather of scaled node rows (no atomics) + W1 matmul -> out_net
// one wave (64 lanes) per net; 4 nets per 256-block. N_NET = 4*5000 exactly.
__global__ void k_aggnet(const float* __restrict__ node_feat,
                         const int* __restrict__ node_deg,
                         const int* __restrict__ net_deg,
                         const int* __restrict__ net_ptr,
                         const int2* __restrict__ csr,
                         const float* __restrict__ W1,
                         const float* __restrict__ b1,
                         float* __restrict__ out_net) {
    __shared__ float srow[4][64];
    int t = threadIdx.x;
    int w = t >> 6, l = t & 63;
    int n = blockIdx.x * 4 + w;
    int beg = net_ptr[n], deg = net_deg[n];
    float acc = 0.f;
    for (int j = 0; j < deg; j++) {
        int v = csr[beg + j].y;
        float dv = (float)node_deg[v]; if (dv < 1.f) dv = 1.f;
        acc += node_feat[v * H_NODE + l] * rsqrtf(dv);
    }
    float dn = (float)deg; if (dn < 1.f) dn = 1.f;
    srow[w][l] = acc * rsqrtf(dn);
    __syncthreads();
    const float* a = srow[w];
    float o_acc = b1[l];
#pragma unroll
    for (int h = 0; h < H_NODE; h++) o_acc += a[h] * W1[h * O_NET + l];
    out_net[n * O_NET + l] = o_acc;
}

// Z[n,k,o] = sum_i y[n,i] * W2[k,i*32+o]; C[n,o] = sum_i y[n,i]*b2[i*32+o]
// register-blocked over ZNPB nets: each W2 value loaded once per block.
#define ZNPB 16
__global__ void k_z(const float* __restrict__ net_feat,
                    const float* __restrict__ W2, const float* __restrict__ b2,
                    float* __restrict__ Z, float* __restrict__ C) {
    __shared__ float sy[ZNPB][H_NET];
    int t = threadIdx.x;
    int base = blockIdx.x * ZNPB;   // 1250 blocks exactly
    for (int i = t; i < ZNPB * H_NET; i += 256)
        sy[i >> 5][i & 31] = net_feat[(base + (i >> 5)) * H_NET + (i & 31)];
    __syncthreads();
    int o = t & 31;
    int k0 = t >> 5, k1 = (t + 256) >> 5;
    float acc0[ZNPB], acc1[ZNPB];
#pragma unroll
    for (int g = 0; g < ZNPB; g++) { acc0[g] = 0.f; acc1[g] = 0.f; }
#pragma unroll 4
    for (int i = 0; i < H_NET; i++) {
        float w0 = W2[k0 * 1024 + i * 32 + o];
        float w1 = W2[k1 * 1024 + i * 32 + o];
#pragma unroll
        for (int g = 0; g < ZNPB; g++) {
            float y = sy[g][i];
            acc0[g] += w0 * y;
            acc1[g] += w1 * y;
        }
    }
#pragma unroll
    for (int g = 0; g < ZNPB; g++) {
        int n = base + g;
        Z[(size_t)n * 512 + t]       = acc0[g];
        Z[(size_t)n * 512 + t + 256] = acc1[g];
    }
    // C: 512 outputs per block (16 nets x 32), 2 per thread
#pragma unroll
    for (int r = 0; r < 2; r++) {
        int idx = t + r * 256;
        int g = idx >> 5, oo = idx & 31;
        float acc = 0.f;
#pragma unroll
        for (int i = 0; i < H_NET; i++) acc += sy[g][i] * b2[i * 32 + oo];
        C[(base + g) * 32 + oo] = acc;
    }
}

// per-net msg: one wave per net, half-wave per edge; Z row L1-resident.
__global__ void k_msgn(const float* __restrict__ pin_feat,
                       const int* __restrict__ net_deg,
                       const int* __restrict__ net_ptr,
                       const int2* __restrict__ csr,
                       const float* __restrict__ Z, const float* __restrict__ C,
                       float* __restrict__ acc_node) {
    int t = threadIdx.x;
    int w = t >> 6, l = t & 63;
    int n = blockIdx.x * 4 + w;    // 5000 blocks exactly
    int half = l >> 5, o = l & 31;
    int beg = net_ptr[n], deg = net_deg[n];
    const float* z = &Z[(size_t)n * 512];
    float c = C[n * 32 + o];
    for (int j = half; j < deg; j += 2) {
        int2 ev = csr[beg + j];
        const float* p = &pin_feat[ev.x * H_PIN];
        float m = c;
#pragma unroll
        for (int k = 0; k < H_PIN; k++) m += p[k] * z[k * 32 + o];
        atomicAdd(&acc_node[ev.y * O_NODE + o], m);
    }
}

__global__ void k_nodeout(const float* __restrict__ acc_node,
                          const int* __restrict__ node_deg,
                          const float* __restrict__ b_nn,
                          float* __restrict__ out_node) {
    int idx = blockIdx.x * blockDim.x + threadIdx.x;
    if (idx >= N_NODE * O_NODE) return;
    int v = idx >> 5, o = idx & 31;
    float d = (float)node_deg[v]; if (d < 1.f) d = 1.f;
    out_node[idx] = acc_node[idx] / d + b_nn[o];
}

extern "C" void kernel_launch(void* const* d_in, const int* in_sizes, int n_in,
                              void* d_out, int out_size, void* d_ws, size_t ws_size,
                              hipStream_t stream) {
    const float* node_feat = (const float*)d_in[0];
    const float* net_feat  = (const float*)d_in[1];
    const float* pin_feat  = (const float*)d_in[2];
    const int*   edge_node = (const int*)d_in[3];
    const int*   edge_net  = (const int*)d_in[4];
    const float* W1        = (const float*)d_in[5];
    const float* b1        = (const float*)d_in[6];
    const float* W2        = (const float*)d_in[7];
    const float* b2        = (const float*)d_in[8];
    const float* b_nn      = (const float*)d_in[9];

    float* out_node = (float*)d_out;                          // [N_NODE*32]
    float* out_net  = out_node + (size_t)N_NODE * O_NODE;     // [N_NET*64]

    char* ws = (char*)d_ws;
    int*   node_deg   = (int*)ws;
    int*   net_deg    = (int*)(ws + OFF_NETDEG);
    float* acc_node   = (float*)(ws + OFF_ACCN);
    int*   net_ptr    = (int*)(ws + OFF_NETPTR);
    int*   net_cursor = (int*)(ws + OFF_CURSOR);
    int2*  csr        = (int2*)(ws + OFF_CSR);
    float* Z          = (float*)(ws + OFF_Z);
    float* C          = (float*)(ws + OFF_C);

    (void)hipMemsetAsync(ws, 0, ZERO_BYTES, stream);

    k_deg<<<(NE + 255) / 256, 256, 0, stream>>>(edge_node, edge_net, node_deg, net_deg);

    k_scan<<<1, 256, 0, stream>>>(net_deg, net_ptr, net_cursor);

    k_fill<<<(NE + 255) / 256, 256, 0, stream>>>(edge_node, edge_net, net_cursor, csr);

    k_z<<<N_NET / ZNPB, 256, 0, stream>>>(net_feat, W2, b2, Z, C);

    k_aggnet<<<N_NET / 4, 256, 0, stream>>>(
        node_feat, node_deg, net_deg, net_ptr, csr, W1, b1, out_net);

    k_msgn<<<N_NET / 4, 256, 0, stream>>>(
        pin_feat, net_deg, net_ptr, csr, Z, C, acc_node);

    k_nodeout<<<(N_NODE * O_NODE + 255) / 256, 256, 0, stream>>>(
        acc_node, node_deg, b_nn, out_node);
}

// Round 5
// 233.061 us; speedup vs baseline: 1.2531x; 1.2123x over previous
//
#include <hip/hip_runtime.h>
#include <hip/hip_bf16.h>

#define N_NODE 100000
#define N_NET  20000
#define NE     200000
#define H_NODE 64
#define H_NET  32
#define H_PIN  16
#define O_NODE 32
#define O_NET  64

// ---------------- workspace layout (bytes, all 16-aligned) ----------------
// zeroed by memset: [0, 480000)
//   node_deg : int   [N_NODE]    off 0          (400000)
//   net_deg  : int   [N_NET]     off 400000     (80000)
// acc_node : float [N_NODE*32]   off 480000     (12800000)  zeroed by k_mix1
// net_ptr  : int   [N_NET+1]     off 13280000   (80004)
// net_cursor:int   [N_NET]       off 13360016   (80000)
// csr      : int2  [NE]          off 13440016   (1600000)
// Z        : float [N_NET*512]   off 15040016   (40960000)
// C        : float [N_NET*32]    off 56000016   (2560000)

#define OFF_ACCN    480000
#define OFF_NETDEG  400000
#define OFF_NETPTR  13280000
#define OFF_CURSOR  13360016
#define OFF_CSR     13440016
#define OFF_Z       15040016
#define OFF_C       56000016
#define ZERO_BYTES  480000

// mixed-grid kernel 1: [0,782) deg atomics | [782,2032) Z/C precompute | [2032,5157) zero acc_node
#define MIX_DEG_BLKS  782
#define MIX_Z_BLKS    1250
#define MIX_ZERO_BLKS 3125
#define ZNPB 16

__global__ void k_mix1(const int* __restrict__ en, const int* __restrict__ em,
                       int* __restrict__ node_deg, int* __restrict__ net_deg,
                       const float* __restrict__ net_feat,
                       const float* __restrict__ W2, const float* __restrict__ b2,
                       float* __restrict__ Z, float* __restrict__ C,
                       float* __restrict__ acc_node) {
    int t = threadIdx.x;
    int b = blockIdx.x;
    if (b < MIX_DEG_BLKS) {
        int e = b * 256 + t;
        if (e < NE) {
            atomicAdd(&node_deg[en[e]], 1);
            atomicAdd(&net_deg[em[e]], 1);
        }
        return;
    }
    if (b < MIX_DEG_BLKS + MIX_Z_BLKS) {
        __shared__ float sy[ZNPB][H_NET];
        int base = (b - MIX_DEG_BLKS) * ZNPB;
        for (int i = t; i < ZNPB * H_NET; i += 256)
            sy[i >> 5][i & 31] = net_feat[(base + (i >> 5)) * H_NET + (i & 31)];
        __syncthreads();
        int o = t & 31;
        int k0 = t >> 5, k1 = (t >> 5) + 8;
        float acc0[ZNPB], acc1[ZNPB];
#pragma unroll
        for (int g = 0; g < ZNPB; g++) { acc0[g] = 0.f; acc1[g] = 0.f; }
#pragma unroll 4
        for (int i = 0; i < H_NET; i++) {
            float w0 = W2[k0 * 1024 + i * 32 + o];
            float w1 = W2[k1 * 1024 + i * 32 + o];
#pragma unroll
            for (int g = 0; g < ZNPB; g++) {
                float y = sy[g][i];
                acc0[g] += w0 * y;
                acc1[g] += w1 * y;
            }
        }
#pragma unroll
        for (int g = 0; g < ZNPB; g++) {
            int n = base + g;
            Z[(size_t)n * 512 + t]       = acc0[g];
            Z[(size_t)n * 512 + t + 256] = acc1[g];
        }
#pragma unroll
        for (int r = 0; r < 2; r++) {
            int idx = t + r * 256;
            int g = idx >> 5, oo = idx & 31;
            float acc = 0.f;
#pragma unroll
            for (int i = 0; i < H_NET; i++) acc += sy[g][i] * b2[i * 32 + oo];
            C[(base + g) * 32 + oo] = acc;
        }
        return;
    }
    // zero acc_node: 3125 blocks x 256 threads x float4 = 12.8MB
    int zi = (b - MIX_DEG_BLKS - MIX_Z_BLKS) * 256 + t;  // < 800000
    ((float4*)acc_node)[zi] = make_float4(0.f, 0.f, 0.f, 0.f);
}

// single-block 1024-thread scan of net_deg -> net_ptr (+cursor). int4 vectorized.
__global__ void k_scan(const int* __restrict__ net_deg, int* __restrict__ net_ptr,
                       int* __restrict__ net_cursor) {
    __shared__ int part[1024];
    int t = threadIdx.x;
    const int4* d4 = (const int4*)net_deg;      // 5000 int4
    int4 v[5];
    int sum = 0;
#pragma unroll
    for (int j = 0; j < 5; j++) {
        int idx = t * 5 + j;
        if (idx < 5000) {
            v[j] = d4[idx];
            sum += v[j].x + v[j].y + v[j].z + v[j].w;
        } else v[j] = make_int4(0, 0, 0, 0);
    }
    part[t] = sum;
    __syncthreads();
    for (int off = 1; off < 1024; off <<= 1) {
        int val = (t >= off) ? part[t - off] : 0;
        __syncthreads();
        part[t] += val;
        __syncthreads();
    }
    int run = (t == 0) ? 0 : part[t - 1];
    int4* p4 = (int4*)net_ptr;
    int4* c4 = (int4*)net_cursor;
#pragma unroll
    for (int j = 0; j < 5; j++) {
        int idx = t * 5 + j;
        if (idx < 5000) {
            int4 w;
            w.x = run; run += v[j].x;
            w.y = run; run += v[j].y;
            w.z = run; run += v[j].z;
            w.w = run; run += v[j].w;
            p4[idx] = w;
            c4[idx] = w;
        }
    }
    if (t == 0) net_ptr[N_NET] = NE;
}

// scatter {edge,node} pairs into net-CSR
__global__ void k_fill(const int* __restrict__ en, const int* __restrict__ em,
                       int* __restrict__ net_cursor, int2* __restrict__ csr) {
    int e = blockIdx.x * blockDim.x + threadIdx.x;
    if (e < NE) {
        int slot = atomicAdd(&net_cursor[em[e]], 1);
        csr[slot] = make_int2(e, en[e]);
    }
}

// fused per-net: gather+W1 matmul -> out_net, then per-edge NNConv messages -> acc_node
__global__ void k_net(const float* __restrict__ node_feat,
                      const int* __restrict__ node_deg,
                      const int* __restrict__ net_deg,
                      const int* __restrict__ net_ptr,
                      const int2* __restrict__ csr,
                      const float* __restrict__ W1,
                      const float* __restrict__ b1,
                      const float* __restrict__ pin_feat,
                      const float* __restrict__ Z, const float* __restrict__ C,
                      float* __restrict__ out_net, float* __restrict__ acc_node) {
    __shared__ float srow[4][64];
    int t = threadIdx.x;
    int w = t >> 6, l = t & 63;
    int n = blockIdx.x * 4 + w;          // 5000 blocks exactly
    int beg = net_ptr[n], deg = net_deg[n];
    // phase A: gather scaled node rows, reduce, W1 matmul
    float acc = 0.f;
    for (int j = 0; j < deg; j++) {
        int v = csr[beg + j].y;
        float dv = (float)node_deg[v]; if (dv < 1.f) dv = 1.f;
        acc += node_feat[v * H_NODE + l] * rsqrtf(dv);
    }
    float dn = (deg < 1) ? 1.f : (float)deg;
    srow[w][l] = acc * rsqrtf(dn);
    __syncthreads();
    const float* a = srow[w];
    float oacc = b1[l];
#pragma unroll
    for (int h = 0; h < H_NODE; h++) oacc += a[h] * W1[h * O_NET + l];
    out_net[n * O_NET + l] = oacc;
    // phase B: per-edge messages (half-wave per edge)
    int half = l >> 5, o = l & 31;
    const float* z = &Z[(size_t)n * 512];
    float c = C[n * 32 + o];
    for (int j = half; j < deg; j += 2) {
        int2 ev = csr[beg + j];
        const float* p = &pin_feat[ev.x * H_PIN];
        float m = c;
#pragma unroll
        for (int k = 0; k < H_PIN; k++) m += p[k] * z[k * 32 + o];
        atomicAdd(&acc_node[ev.y * O_NODE + o], m);
    }
}

// node_out = acc_node/deg + b_nn, float4-vectorized
__global__ void k_nodeout(const float* __restrict__ acc_node,
                          const int* __restrict__ node_deg,
                          const float* __restrict__ b_nn,
                          float* __restrict__ out_node) {
    int idx = blockIdx.x * blockDim.x + threadIdx.x;   // < 800000 float4s
    if (idx >= N_NODE * O_NODE / 4) return;
    int v = idx >> 3, o4 = idx & 7;
    float d = (float)node_deg[v]; if (d < 1.f) d = 1.f;
    float inv = 1.f / d;
    float4 a = ((const float4*)acc_node)[idx];
    float4 bb = ((const float4*)b_nn)[o4];
    float4 r;
    r.x = a.x * inv + bb.x;
    r.y = a.y * inv + bb.y;
    r.z = a.z * inv + bb.z;
    r.w = a.w * inv + bb.w;
    ((float4*)out_node)[idx] = r;
}

extern "C" void kernel_launch(void* const* d_in, const int* in_sizes, int n_in,
                              void* d_out, int out_size, void* d_ws, size_t ws_size,
                              hipStream_t stream) {
    const float* node_feat = (const float*)d_in[0];
    const float* net_feat  = (const float*)d_in[1];
    const float* pin_feat  = (const float*)d_in[2];
    const int*   edge_node = (const int*)d_in[3];
    const int*   edge_net  = (const int*)d_in[4];
    const float* W1        = (const float*)d_in[5];
    const float* b1        = (const float*)d_in[6];
    const float* W2        = (const float*)d_in[7];
    const float* b2        = (const float*)d_in[8];
    const float* b_nn      = (const float*)d_in[9];

    float* out_node = (float*)d_out;                          // [N_NODE*32]
    float* out_net  = out_node + (size_t)N_NODE * O_NODE;     // [N_NET*64]

    char* ws = (char*)d_ws;
    int*   node_deg   = (int*)ws;
    int*   net_deg    = (int*)(ws + OFF_NETDEG);
    float* acc_node   = (float*)(ws + OFF_ACCN);
    int*   net_ptr    = (int*)(ws + OFF_NETPTR);
    int*   net_cursor = (int*)(ws + OFF_CURSOR);
    int2*  csr        = (int2*)(ws + OFF_CSR);
    float* Z          = (float*)(ws + OFF_Z);
    float* C          = (float*)(ws + OFF_C);

    (void)hipMemsetAsync(ws, 0, ZERO_BYTES, stream);

    k_mix1<<<MIX_DEG_BLKS + MIX_Z_BLKS + MIX_ZERO_BLKS, 256, 0, stream>>>(
        edge_node, edge_net, node_deg, net_deg,
        net_feat, W2, b2, Z, C, acc_node);

    k_scan<<<1, 1024, 0, stream>>>(net_deg, net_ptr, net_cursor);

    k_fill<<<(NE + 255) / 256, 256, 0, stream>>>(edge_node, edge_net, net_cursor, csr);

    k_net<<<N_NET / 4, 256, 0, stream>>>(
        node_feat, node_deg, net_deg, net_ptr, csr, W1, b1,
        pin_feat, Z, C, out_net, acc_node);

    k_nodeout<<<(N_NODE * O_NODE / 4 + 255) / 256, 256, 0, stream>>>(
        acc_node, node_deg, b_nn, out_node);
}

// Round 7
// 201.129 us; speedup vs baseline: 1.4520x; 1.1588x over previous
//
#include <hip/hip_runtime.h>
#include <hip/hip_bf16.h>

#define N_NODE 100000
#define N_NET  20000
#define NE     200000
#define H_NODE 64
#define H_NET  32
#define H_PIN  16
#define O_NODE 32
#define O_NET  64

// ---------------- workspace layout (bytes, 16-aligned) ----------------
// zeroed by memset: [0, 480000)
//   node_deg : int   [N_NODE]    off 0          (400000)
//   net_deg  : int   [N_NET]     off 400000     (80000)
// acc_node : float [N_NODE*32]   off 480000     (12800000)  zeroed by k_pre
// net_ptr  : int   [N_NET+1]     off 13280000   (80004)
// net_cursor:int   [N_NET]       off 13360016   (80000)
// csr      : int2  [NE]          off 13440016   (1600000)   total ~15.1MB

#define OFF_NETDEG  400000
#define OFF_ACCN    480000
#define OFF_NETPTR  13280000
#define OFF_CURSOR  13360016
#define OFF_CSR     13440016
#define ZERO_BYTES  480000

// mixed grid: [0,782) deg atomics | [782,3907) zero acc_node (float4)
#define PRE_DEG_BLKS  782
#define PRE_ZERO_BLKS 3125

__global__ void k_pre(const int* __restrict__ en, const int* __restrict__ em,
                      int* __restrict__ node_deg, int* __restrict__ net_deg,
                      float* __restrict__ acc_node) {
    int t = threadIdx.x, b = blockIdx.x;
    if (b < PRE_DEG_BLKS) {
        int e = b * 256 + t;
        if (e < NE) {
            atomicAdd(&node_deg[en[e]], 1);
            atomicAdd(&net_deg[em[e]], 1);
        }
        return;
    }
    int zi = (b - PRE_DEG_BLKS) * 256 + t;   // < 800000 float4s
    ((float4*)acc_node)[zi] = make_float4(0.f, 0.f, 0.f, 0.f);
}

// single-block 1024-thread scan of net_deg -> net_ptr (+cursor). int4 vectorized.
__global__ void k_scan(const int* __restrict__ net_deg, int* __restrict__ net_ptr,
                       int* __restrict__ net_cursor) {
    __shared__ int part[1024];
    int t = threadIdx.x;
    const int4* d4 = (const int4*)net_deg;      // 5000 int4
    int4 v[5];
    int sum = 0;
#pragma unroll
    for (int j = 0; j < 5; j++) {
        int idx = t * 5 + j;
        if (idx < 5000) {
            v[j] = d4[idx];
            sum += v[j].x + v[j].y + v[j].z + v[j].w;
        } else v[j] = make_int4(0, 0, 0, 0);
    }
    part[t] = sum;
    __syncthreads();
    for (int off = 1; off < 1024; off <<= 1) {
        int val = (t >= off) ? part[t - off] : 0;
        __syncthreads();
        part[t] += val;
        __syncthreads();
    }
    int run = (t == 0) ? 0 : part[t - 1];
    int4* p4 = (int4*)net_ptr;
    int4* c4 = (int4*)net_cursor;
#pragma unroll
    for (int j = 0; j < 5; j++) {
        int idx = t * 5 + j;
        if (idx < 5000) {
            int4 w;
            w.x = run; run += v[j].x;
            w.y = run; run += v[j].y;
            w.z = run; run += v[j].z;
            w.w = run; run += v[j].w;
            p4[idx] = w;
            c4[idx] = w;
        }
    }
    if (t == 0) net_ptr[N_NET] = NE;
}

__global__ void k_fill(const int* __restrict__ en, const int* __restrict__ em,
                       int* __restrict__ net_cursor, int2* __restrict__ csr) {
    int e = blockIdx.x * blockDim.x + threadIdx.x;
    if (e < NE) {
        int slot = atomicAdd(&net_cursor[em[e]], 1);
        csr[slot] = make_int2(e, en[e]);
    }
}

// fused per-net kernel: 4 nets/block, one wave each.
// phase 0: cooperative Z,C into LDS (W2 read once per block, L2-hot)
// phase A: MLP-unrolled gather + W1 matmul -> out_net
// phase B: per-edge NNConv messages (z from LDS) -> acc_node atomics
// NOTE: every __shfl in this kernel executes with the FULL wave converged
// (uniform trip counts; tails handled by clamped source + predicated effects).
// Divergent-EXEC shfl reads from inactive lanes are UNDEFINED on gfx950.
__global__ void k_net(const float* __restrict__ node_feat,
                      const float* __restrict__ net_feat,
                      const int* __restrict__ node_deg,
                      const int* __restrict__ net_deg,
                      const int* __restrict__ net_ptr,
                      const int2* __restrict__ csr,
                      const float* __restrict__ W1,
                      const float* __restrict__ b1,
                      const float* __restrict__ W2,
                      const float* __restrict__ b2,
                      const float* __restrict__ pin_feat,
                      float* __restrict__ out_net, float* __restrict__ acc_node) {
    __shared__ float sZ[4][512];   // 8 KB
    __shared__ float sC[4][32];
    __shared__ float sy[4][32];
    __shared__ float srow[4][64];
    int t = threadIdx.x;
    int nb = blockIdx.x * 4;       // 5000 blocks exactly
    // ---- phase 0: load y, compute Z and C into LDS ----
    if (t < 128) sy[t >> 5][t & 31] = net_feat[(nb + (t >> 5)) * H_NET + (t & 31)];
    __syncthreads();
    {
        int o = t & 31, k0 = t >> 5, k1 = k0 + 8;
        float a0[4] = {0.f, 0.f, 0.f, 0.f}, a1[4] = {0.f, 0.f, 0.f, 0.f};
#pragma unroll 4
        for (int i = 0; i < H_NET; i++) {
            float w0 = W2[k0 * 1024 + i * 32 + o];
            float w1 = W2[k1 * 1024 + i * 32 + o];
#pragma unroll
            for (int g = 0; g < 4; g++) {
                a0[g] += w0 * sy[g][i];
                a1[g] += w1 * sy[g][i];
            }
        }
#pragma unroll
        for (int g = 0; g < 4; g++) {
            sZ[g][t] = a0[g];
            sZ[g][t + 256] = a1[g];
        }
        if (t < 128) {
            int g = t >> 5, oo = t & 31;
            float acc = 0.f;
#pragma unroll
            for (int i = 0; i < H_NET; i++) acc += sy[g][i] * b2[i * 32 + oo];
            sC[g][oo] = acc;
        }
    }
    // ---- phase A: gather + W1 matmul (j sequence wave-uniform -> shfl safe) ----
    int w = t >> 6, l = t & 63;
    int n = nb + w;
    int beg = net_ptr[n], deg = net_deg[n];
    float acc = 0.f;
    for (int j0 = 0; j0 < deg; j0 += 64) {
        int cnt = deg - j0; if (cnt > 64) cnt = 64;
        int vj = 0; float sj = 0.f;
        if (l < cnt) {
            int2 ev = csr[beg + j0 + l];
            vj = ev.y;
            float dv = (float)node_deg[vj]; if (dv < 1.f) dv = 1.f;
            sj = rsqrtf(dv);
        }
        int j = 0;
        for (; j + 4 <= cnt; j += 4) {
            int v0 = __shfl(vj, j),     v1 = __shfl(vj, j + 1);
            int v2 = __shfl(vj, j + 2), v3 = __shfl(vj, j + 3);
            float s0 = __shfl(sj, j),     s1 = __shfl(sj, j + 1);
            float s2 = __shfl(sj, j + 2), s3 = __shfl(sj, j + 3);
            float x0 = node_feat[(size_t)v0 * H_NODE + l];
            float x1 = node_feat[(size_t)v1 * H_NODE + l];
            float x2 = node_feat[(size_t)v2 * H_NODE + l];
            float x3 = node_feat[(size_t)v3 * H_NODE + l];
            acc += x0 * s0; acc += x1 * s1; acc += x2 * s2; acc += x3 * s3;
        }
        for (; j < cnt; j++) {
            int v0 = __shfl(vj, j); float s0 = __shfl(sj, j);
            acc += node_feat[(size_t)v0 * H_NODE + l] * s0;
        }
    }
    float dn = (deg < 1) ? 1.f : (float)deg;
    srow[w][l] = acc * rsqrtf(dn);
    __syncthreads();   // covers srow AND sZ/sC writes
    {
        const float* a = srow[w];
        float oacc = b1[l];
#pragma unroll
        for (int h = 0; h < H_NODE; h++) oacc += a[h] * W1[h * O_NET + l];
        out_net[n * O_NET + l] = oacc;
    }
    // ---- phase B: per-edge messages, uniform trip count, full-wave shfl ----
    // iteration j covers edges j..j+3: half0 -> j, j+2 ; half1 -> j+1, j+3
    int half = l >> 5, o = l & 31;
    const float* zrow = sZ[w];
    float c = sC[w][o];
    for (int j0 = 0; j0 < deg; j0 += 64) {
        int cnt = deg - j0; if (cnt > 64) cnt = 64;   // cnt >= 1 here
        int ej = 0, vj = 0;
        if (l < cnt) {
            int2 ev = csr[beg + j0 + l];
            ej = ev.x; vj = ev.y;
        }
        for (int j = 0; j < cnt; j += 4) {
            int jjA = j + half;
            int jjB = j + 2 + half;
            int sA = (jjA < cnt) ? jjA : cnt - 1;   // clamp: keep loads in-bounds
            int sB = (jjB < cnt) ? jjB : cnt - 1;
            int eA = __shfl(ej, sA), vA = __shfl(vj, sA);
            int eB = __shfl(ej, sB), vB = __shfl(vj, sB);
            const float* pA = &pin_feat[(size_t)eA * H_PIN];
            const float* pB = &pin_feat[(size_t)eB * H_PIN];
            float mA = c, mB = c;
#pragma unroll
            for (int k = 0; k < H_PIN; k++) {
                mA += pA[k] * zrow[k * 32 + o];
                mB += pB[k] * zrow[k * 32 + o];
            }
            if (jjA < cnt) atomicAdd(&acc_node[(size_t)vA * O_NODE + o], mA);
            if (jjB < cnt) atomicAdd(&acc_node[(size_t)vB * O_NODE + o], mB);
        }
    }
}

// node_out = acc_node/deg + b_nn, float4-vectorized
__global__ void k_nodeout(const float* __restrict__ acc_node,
                          const int* __restrict__ node_deg,
                          const float* __restrict__ b_nn,
                          float* __restrict__ out_node) {
    int idx = blockIdx.x * blockDim.x + threadIdx.x;   // < 800000 float4s
    if (idx >= N_NODE * O_NODE / 4) return;
    int v = idx >> 3, o4 = idx & 7;
    float d = (float)node_deg[v]; if (d < 1.f) d = 1.f;
    float inv = 1.f / d;
    float4 a = ((const float4*)acc_node)[idx];
    float4 bb = ((const float4*)b_nn)[o4];
    float4 r;
    r.x = a.x * inv + bb.x;
    r.y = a.y * inv + bb.y;
    r.z = a.z * inv + bb.z;
    r.w = a.w * inv + bb.w;
    ((float4*)out_node)[idx] = r;
}

extern "C" void kernel_launch(void* const* d_in, const int* in_sizes, int n_in,
                              void* d_out, int out_size, void* d_ws, size_t ws_size,
                              hipStream_t stream) {
    const float* node_feat = (const float*)d_in[0];
    const float* net_feat  = (const float*)d_in[1];
    const float* pin_feat  = (const float*)d_in[2];
    const int*   edge_node = (const int*)d_in[3];
    const int*   edge_net  = (const int*)d_in[4];
    const float* W1        = (const float*)d_in[5];
    const float* b1        = (const float*)d_in[6];
    const float* W2        = (const float*)d_in[7];
    const float* b2        = (const float*)d_in[8];
    const float* b_nn      = (const float*)d_in[9];

    float* out_node = (float*)d_out;                          // [N_NODE*32]
    float* out_net  = out_node + (size_t)N_NODE * O_NODE;     // [N_NET*64]

    char* ws = (char*)d_ws;
    int*   node_deg   = (int*)ws;
    int*   net_deg    = (int*)(ws + OFF_NETDEG);
    float* acc_node   = (float*)(ws + OFF_ACCN);
    int*   net_ptr    = (int*)(ws + OFF_NETPTR);
    int*   net_cursor = (int*)(ws + OFF_CURSOR);
    int2*  csr        = (int2*)(ws + OFF_CSR);

    (void)hipMemsetAsync(ws, 0, ZERO_BYTES, stream);

    k_pre<<<PRE_DEG_BLKS + PRE_ZERO_BLKS, 256, 0, stream>>>(
        edge_node, edge_net, node_deg, net_deg, acc_node);

    k_scan<<<1, 1024, 0, stream>>>(net_deg, net_ptr, net_cursor);

    k_fill<<<(NE + 255) / 256, 256, 0, stream>>>(edge_node, edge_net, net_cursor, csr);

    k_net<<<N_NET / 4, 256, 0, stream>>>(
        node_feat, net_feat, node_deg, net_deg, net_ptr, csr,
        W1, b1, W2, b2, pin_feat, out_net, acc_node);

    k_nodeout<<<(N_NODE * O_NODE / 4 + 255) / 256, 256, 0, stream>>>(
        acc_node, node_deg, b_nn, out_node);
}